// Round 1
// baseline (797.973 us; speedup 1.0000x reference)
//
#include <hip/hip_runtime.h>

#define HH 512
#define WW 512
#define HWC (HH * WW)          // 262144 = 2^18
#define NV 50000
#define NB 4

static __device__ __forceinline__ float4 ld4(const float* p) {
    return *reinterpret_cast<const float4*>(p);
}

// ---------------------------------------------------------------------------
// K1: scatter voxel indices into dense coord->index grids
// grids layout: [set(0=li,1=ra)][b][HWC], pre-filled with -1
// ---------------------------------------------------------------------------
__global__ void k_grid(const int* __restrict__ li_coors, const int* __restrict__ ra_coors,
                       int* __restrict__ grids) {
    int t = blockIdx.x * blockDim.x + threadIdx.x;
    if (t >= 2 * NB * NV) return;
    int set = t / (NB * NV);
    int r2 = t - set * (NB * NV);
    int b = r2 / NV;
    int n = r2 - b * NV;
    const int* co = (set == 0 ? li_coors : ra_coors) + (size_t)(b * NV + n) * 2;
    grids[(set * NB + b) * HWC + co[0] * WW + co[1]] = n;
}

// ---------------------------------------------------------------------------
// K2: pre-project K,V for every kv row of both branches.
// KV layout: [br][b][n][64]  (0..31 = K row, 32..63 = V row)
// branch 0: kv = ra_feats with w_qkv1 ; branch 1: kv = li_feats with w_qkv2
// One wave per row per iteration: lanes 0..31 -> K[j], lanes 32..63 -> V[j].
// ---------------------------------------------------------------------------
__launch_bounds__(256)
__global__ void k_proj(const float* __restrict__ li_feats, const float* __restrict__ ra_feats,
                       const float* __restrict__ w_qkv1, const float* __restrict__ b_qkv1,
                       const float* __restrict__ w_qkv2, const float* __restrict__ b_qkv2,
                       float* __restrict__ KV) {
    const int br   = blockIdx.x & 1;
    const int lane = threadIdx.x & 63;
    const int j    = lane & 31;
    const int half = lane >> 5;  // 0 = K, 1 = V
    const float* wqkv = br ? w_qkv2 : w_qkv1;
    const float* bqkv = br ? b_qkv2 : b_qkv1;
    const float* kvf  = br ? li_feats : ra_feats;
    const int wrow = 32 + half * 32 + j;  // wk rows 32..63, wv rows 64..95
    float4 wr[8];
#pragma unroll
    for (int i = 0; i < 8; ++i) wr[i] = ld4(wqkv + wrow * 32 + i * 4);
    const float bias = bqkv[wrow];

    int wave   = (blockIdx.x >> 1) * (blockDim.x >> 6) + (threadIdx.x >> 6);
    int stride = (gridDim.x >> 1) * (blockDim.x >> 6);
    float* KVb = KV + (size_t)br * NB * NV * 64;
    for (int row = wave; row < NB * NV; row += stride) {
        const float* rp = kvf + (size_t)row * 32;
        float acc = bias;
#pragma unroll
        for (int i = 0; i < 8; ++i) {
            float4 rv = ld4(rp + i * 4);
            float4 w = wr[i];
            acc += w.x * rv.x + w.y * rv.y + w.z * rv.z + w.w * rv.w;
        }
        KVb[(size_t)row * 64 + lane] = acc;
    }
}

// ---------------------------------------------------------------------------
// K3: fused per-query attention. 32 lanes per query (channel j), 8 queries/block.
// res layout: [br][b][n][32] = q_feat + attn_out
// ---------------------------------------------------------------------------
__launch_bounds__(256)
__global__ void k_attn(const float* __restrict__ li_feats, const float* __restrict__ ra_feats,
                       const int* __restrict__ li_coors, const int* __restrict__ ra_coors,
                       const float* __restrict__ w_qkv1, const float* __restrict__ b_qkv1,
                       const float* __restrict__ w_out1, const float* __restrict__ b_out1,
                       const float* __restrict__ w_qkv2, const float* __restrict__ b_qkv2,
                       const float* __restrict__ w_out2, const float* __restrict__ b_out2,
                       const int* __restrict__ grids, const float* __restrict__ KV,
                       float* __restrict__ res) {
    __shared__ float q_lds[8][32];
    __shared__ float o_lds[8][32];
    const int g = threadIdx.x >> 5;
    const int j = threadIdx.x & 31;
    const int qid = blockIdx.x * 8 + g;
    const int br  = (qid >= NB * NV) ? 1 : 0;
    const int rem = qid - br * NB * NV;
    const int b   = rem / NV;
    const int n   = rem - b * NV;

    const float* qf   = br ? ra_feats : li_feats;
    const int*   qc   = br ? ra_coors : li_coors;
    const float* wqkv = br ? w_qkv2 : w_qkv1;
    const float* bqkv = br ? b_qkv2 : b_qkv1;
    const float* wout = br ? w_out2 : w_out1;
    const float* bout = br ? b_out2 : b_out1;
    const int* kvgrid  = grids + ((br == 0 ? 1 : 0) * NB + b) * HWC;  // kv coords grid
    const float* KVb   = KV + ((size_t)br * NB + b) * (size_t)NV * 64;

    float4 wqr[8], wor[8];
#pragma unroll
    for (int i = 0; i < 8; ++i) {
        wqr[i] = ld4(wqkv + j * 32 + i * 4);   // wq row j
        wor[i] = ld4(wout + j * 32 + i * 4);   // w_out row j
    }
    const float bq = bqkv[j], bk = bqkv[32 + j], bv = bqkv[64 + j], bo = bout[j];

    const float qv = qf[(size_t)(b * NV + n) * 32 + j];
    q_lds[g][j] = qv;
    __syncthreads();

    float Q = bq;
#pragma unroll
    for (int i = 0; i < 8; ++i) {
        float4 qd = *reinterpret_cast<const float4*>(&q_lds[g][i * 4]);
        float4 w = wqr[i];
        Q += w.x * qd.x + w.y * qd.y + w.z * qd.z + w.w * qd.w;
    }

    const int r0 = qc[(size_t)(b * NV + n) * 2];
    const int c0 = qc[(size_t)(b * NV + n) * 2 + 1];

    const int drs[9] = {0, -1, 1, 0, -1, 1, 0, -1, 1};
    const int dcs[9] = {0, 0, 0, 1, 1, 1, -1, -1, -1};
    float sc[9], Vv[9];
#pragma unroll
    for (int k = 0; k < 9; ++k) {
        int rr = r0 + drs[k], cc = c0 + dcs[k];
        bool valid = (rr >= 0) & (rr < HH) & (cc >= 0) & (cc < WW);
        int idx = valid ? kvgrid[rr * WW + cc] : -1;
        float Kv, Vx;
        if (idx >= 0) {
            const float* kvp = KVb + (size_t)idx * 64;
            Kv = kvp[j];
            Vx = kvp[32 + j];
        } else {
            Kv = bk;   // zero key rows still get the bias
            Vx = bv;
        }
        Vv[k] = Vx;
        float p = Q * Kv;
        p += __shfl_xor(p, 1, 16);
        p += __shfl_xor(p, 2, 16);
        p += __shfl_xor(p, 4, 16);
        p += __shfl_xor(p, 8, 16);
        sc[k] = p * 0.25f;  // 1/sqrt(HD=16)
    }
    float m = sc[0];
#pragma unroll
    for (int k = 1; k < 9; ++k) m = fmaxf(m, sc[k]);
    float sum = 0.f;
#pragma unroll
    for (int k = 0; k < 9; ++k) { sc[k] = __expf(sc[k] - m); sum += sc[k]; }
    const float inv = 1.0f / sum;
    float o = 0.f;
#pragma unroll
    for (int k = 0; k < 9; ++k) o += sc[k] * Vv[k];
    o *= inv;
    o_lds[g][j] = o;
    __syncthreads();

    float out = bo;
#pragma unroll
    for (int i = 0; i < 8; ++i) {
        float4 od = *reinterpret_cast<const float4*>(&o_lds[g][i * 4]);
        float4 w = wor[i];
        out += w.x * od.x + w.y * od.y + w.z * od.z + w.w * od.w;
    }
    res[(size_t)qid * 32 + j] = qv + out;
}

// ---------------------------------------------------------------------------
// K4: densify (inverted scatter). One thread per output cell; writes all 32
// channel planes coalesced, gathers the 128B res row (or zeros).
// ---------------------------------------------------------------------------
__launch_bounds__(256)
__global__ void k_densify(const int* __restrict__ grids, const float* __restrict__ res,
                          float* __restrict__ out) {
    int t = blockIdx.x * 256 + threadIdx.x;  // 0 .. 2*NB*HWC-1
    int plane = t >> 18;                     // (br*NB + b)
    int s = t & (HWC - 1);
    int gidx = grids[t];                     // query grid (set==branch)
    float4 v[8];
    if (gidx >= 0) {
        const float* rp = res + ((size_t)plane * NV + gidx) * 32;
#pragma unroll
        for (int i = 0; i < 8; ++i) v[i] = ld4(rp + i * 4);
    } else {
#pragma unroll
        for (int i = 0; i < 8; ++i) v[i] = make_float4(0.f, 0.f, 0.f, 0.f);
    }
    float* ob = out + (size_t)plane * 32 * HWC + s;
#pragma unroll
    for (int i = 0; i < 8; ++i) {
        ob[(size_t)(4 * i + 0) * HWC] = v[i].x;
        ob[(size_t)(4 * i + 1) * HWC] = v[i].y;
        ob[(size_t)(4 * i + 2) * HWC] = v[i].z;
        ob[(size_t)(4 * i + 3) * HWC] = v[i].w;
    }
}

// ---------------------------------------------------------------------------
extern "C" void kernel_launch(void* const* d_in, const int* in_sizes, int n_in,
                              void* d_out, int out_size, void* d_ws, size_t ws_size,
                              hipStream_t stream) {
    const float* li_feats = (const float*)d_in[0];
    const int*   li_coors = (const int*)d_in[1];
    const float* ra_feats = (const float*)d_in[2];
    const int*   ra_coors = (const int*)d_in[3];
    const float* w_qkv1 = (const float*)d_in[4];
    const float* b_qkv1 = (const float*)d_in[5];
    const float* w_out1 = (const float*)d_in[6];
    const float* b_out1 = (const float*)d_in[7];
    const float* w_qkv2 = (const float*)d_in[8];
    const float* b_qkv2 = (const float*)d_in[9];
    const float* w_out2 = (const float*)d_in[10];
    const float* b_out2 = (const float*)d_in[11];
    float* out = (float*)d_out;

    char* ws = (char*)d_ws;
    int*   grids = (int*)ws;                                        // 8 MB
    float* KV    = (float*)(ws + (size_t)2 * NB * HWC * 4);         // 102.4 MB
    float* res   = (float*)(ws + (size_t)2 * NB * HWC * 4
                               + (size_t)2 * NB * NV * 64 * 4);     // 51.2 MB

    hipMemsetAsync(grids, 0xFF, (size_t)2 * NB * HWC * 4, stream);  // all -1

    k_grid<<<(2 * NB * NV + 255) / 256, 256, 0, stream>>>(li_coors, ra_coors, grids);

    k_proj<<<1024, 256, 0, stream>>>(li_feats, ra_feats,
                                     w_qkv1, b_qkv1, w_qkv2, b_qkv2, KV);

    k_attn<<<(2 * NB * NV) / 8, 256, 0, stream>>>(
        li_feats, ra_feats, li_coors, ra_coors,
        w_qkv1, b_qkv1, w_out1, b_out1,
        w_qkv2, b_qkv2, w_out2, b_out2,
        grids, KV, res);

    k_densify<<<(2 * NB * HWC) / 256, 256, 0, stream>>>(grids, res, out);
}